// Round 3
// baseline (799.517 us; speedup 1.0000x reference)
//
#include <hip/hip_runtime.h>
#include <stddef.h>

#define BS 8192
#define NNODE 25
#define TT 128
#define TCH 16                 // t-steps per staged LDS window
#define NW (TT / TCH)          // 8 windows
#define CPB 32                 // chains per block (8 lanes per chain)
#define XPAD 33                // chain-dim stride: 33 -> bank spread
#define LOG2E 1.4426950408889634f

typedef float v2f __attribute__((ext_vector_type(2)));
typedef float v4f __attribute__((ext_vector_type(4)));

// Raw v_exp_f32 / v_rcp_f32. (__exp2f collides with glibc math.h macros.)
__device__ __forceinline__ float ex2(float x) { return __builtin_amdgcn_exp2f(x); }
__device__ __forceinline__ float rcp_(float x) { return __builtin_amdgcn_rcpf(x); }

// Static device buffers (no ws_size dependence). Fully rewritten every call.
__device__ float g_hf[NNODE * BS * 4];  // (i, b, d)
__device__ float g_hb[NNODE * BS * 4];

// Broadcast lane K of each quad (lanes 4q..4q+3) via DPP quad_perm — 1 VALU op.
template <int K>
__device__ __forceinline__ float bcast4(float v) {
  int s = __builtin_bit_cast(int, v);
  int r = __builtin_amdgcn_update_dpp(0, s, (K * 0x55), 0xF, 0xF, true);
  return __builtin_bit_cast(float, r);
}

// Exchange a packed pair with the partner half-quad (lane ^ 4).
// Uses __shfl_xor (compiler-owned convergent lowering) instead of raw
// ds_swizzle: R2's raw-swizzle version miscomputed; this removes the only
// hand-rolled lane-cross primitive from the new datapath.
__device__ __forceinline__ v2f xch4(v2f v) {
  return v2f{__shfl_xor(v.x, 4), __shfl_xor(v.y, 4)};
}

// Branch-proof bitwise select: m all-ones -> a, m zero -> b. Lowers to
// v_bfi_b32; cannot be unswitched into divergent control flow (which would
// break lane-exchange EXEC assumptions the way R2's ternary selects could).
__device__ __forceinline__ float bitsel(int m, float a, float b) {
  const int r = (__builtin_bit_cast(int, a) & m) | (__builtin_bit_cast(int, b) & ~m);
  return __builtin_bit_cast(float, r);
}

// Packed gate accumulate: G += splat(s) * w  (one v_pk_fma_f32).
__device__ __forceinline__ void acc1(v2f& G, float s, v2f w) {
  v2f sv = {s, s};
  G = __builtin_elementwise_fma(sv, w, G);
}

// Full recurrence for one direction; DIR compile-time so staging index math
// and neighbor-row mapping are static.
//
// 8-lane chain scheme: lanes 8q..8q+7 serve one (batch) chain. Within that
// group, quad {0..3} = "A half" computes the packed (ig,fg) gate pair for
// features 0..3; quad {4..7} = "B half" computes (og,cc). h/c are duplicated
// across halves (both compute the identical tail), so quad_perm broadcasts
// keep working per half. Gate-FMA work halves per lane; the exp pairs are
// exchanged across halves with one __shfl_xor(.,4) per register. This
// doubles resident waves (2048 total = 2/SIMD) to fill issue stalls that
// intra-wave scheduling could not (R1 null result).
template <int DIR>
__device__ __forceinline__ void rnn_run(
    int tid, const float* __restrict__ xblk, float* __restrict__ xs,
    const float* __restrict__ h0, const float* __restrict__ c0,
    const float* __restrict__ Wx, const float* __restrict__ Wh,
    const float* __restrict__ Wn, const float* __restrict__ Bb,
    float* __restrict__ ho, int b) {
  const int d = tid & 3;            // feature
  const int half = (tid >> 2) & 1;  // 0: (ig,fg)  1: (og,cc)
  const int hm = -half;             // 0 or 0xFFFFFFFF, for bitsel
  const int bl = tid >> 3;          // local chain 0..31
  const int col0 = half * 8 + d;    // gate column for G.x
  const int col1 = col0 + 4;        // gate column for G.y
  const float s0 = -LOG2E;                            // ig/fg/og prescale
  const float s1 = half ? (2.0f * LOG2E) : (-LOG2E);  // cc gets 2*log2e

  // Packed prescaled weights. Input order k: 0=x, 1..4=h feats, 5..8=nb
  // [up,dn,lf,rt]. fwd rows [up,dn,lf,rt]=0,1,2,3; bwd order is [up,dn,rt,lf]
  // so lf-value uses row 3, rt-value row 2. Identical constants to the 4-lane
  // kernel's wA/wB (A half == old wA, B half == old wB) -> bit-exact gates.
  v2f w[9];
  w[0] = v2f{s0 * Wx[col0], s1 * Wx[col1]};
#pragma unroll
  for (int k = 0; k < 4; ++k)
    w[1 + k] = v2f{s0 * Wh[k * 16 + col0], s1 * Wh[k * 16 + col1]};
  const int nrow[4] = {0, 1, DIR ? 3 : 2, DIR ? 2 : 3};
#pragma unroll
  for (int k = 0; k < 4; ++k)
    w[5 + k] = v2f{s0 * Wn[nrow[k] * 16 + col0], s1 * Wn[nrow[k] * 16 + col1]};
  const v2f bv = {s0 * Bb[col0], s1 * Bb[col1]};

  float h[NNODE], c[NNODE], b3[NNODE];
#pragma unroll
  for (int i = 0; i < NNODE; ++i) {
    h[i] = h0[(i * BS + b) * 4 + d];
    c[i] = c0[(i * BS + b) * 4 + d];
    b3[i] = bcast4<3>(h[i]);
  }

  for (int w8 = 0; w8 < NW; ++w8) {
    __syncthreads();  // previous window's reads complete before overwrite
    // Stage window w8: logical steps s=16*w8..16*w8+15 (bwd: t = 127-s).
    // 3200 float4 segments (chain, node, t-quad); 64B-aligned, every byte
    // consumed, consecutive lanes -> consecutive 16B -> coalesced.
    const int tb_base = DIR ? (TT - TCH - TCH * w8) : (TCH * w8);
#pragma unroll
    for (int r = 0; r < 13; ++r) {
      const int seg = tid + 256 * r;  // 0..3199 (last iter half-active)
      if (seg < CPB * NNODE * 4) {
        const int t4 = seg & 3;
        const int rest = seg >> 2;       // 0..799
        const int sbl = rest / 25;       // chain
        const int sii = rest - sbl * 25; // node
        const v4f v = *(const v4f*)(xblk + ((size_t)sbl * NNODE + sii) * TT +
                                    tb_base + 4 * t4);
#pragma unroll
        for (int j = 0; j < 4; ++j) {
          const int kk = DIR ? (15 - 4 * t4 - j) : (4 * t4 + j);
          xs[(kk * NNODE + sii) * XPAD + sbl] = v[j];
        }
      }
    }
    __syncthreads();

#pragma unroll 1  // keep I$ small: body is the unrolled 25-node step
    for (int kk = 0; kk < TCH; ++kk) {
      // Batch the 25 x reads (8-lane broadcast per chain, conflict-free).
      float xq[NNODE];
#pragma unroll
      for (int i = 0; i < NNODE; ++i) xq[i] = xs[(kk * NNODE + i) * XPAD + bl];

#pragma unroll
      for (int i = 0; i < NNODE; ++i) {
        // Own features 0..2 via quad broadcast; feature 3 via b3[].
        const float f0 = bcast4<0>(h[i]);
        const float f1 = bcast4<1>(h[i]);
        const float f2 = bcast4<2>(h[i]);

        v2f G = bv;
        acc1(G, xq[i], w[0]);
        acc1(G, f0, w[1]);
        acc1(G, f1, w[2]);
        acc1(G, f2, w[3]);
        acc1(G, b3[i], w[4]);
        // up/lf updated this t (j<i), dn/rt prev-t (j>i). Out-of-range terms
        // are exact zeros -> statically skipped. lf/rt row-wrap faithful.
        if (i >= 5) acc1(G, b3[i - 5], w[5]);  // up
        if (i < 20) acc1(G, b3[i + 5], w[6]);  // dn
        if (i >= 1) acc1(G, b3[i - 1], w[7]);  // lf (serial dep)
        if (i < 24) acc1(G, b3[i + 1], w[8]);  // rt

        // A half: G = (-log2e*ig, -log2e*fg); B half: (-log2e*og, 2log2e*cc).
        const v2f Em = {ex2(G.x), ex2(G.y)};
        const v2f Sw = xch4(Em);  // partner half's pair
        // EA = (e^-ig, e^-fg), EB = (e^-og, e^{2cc}) on ALL lanes, selected
        // via branch-proof bit ops (hm = -half).
        const float Ei = bitsel(hm, Sw.x, Em.x);
        const float Ef = bitsel(hm, Sw.y, Em.y);
        const float Eo = bitsel(hm, Em.x, Sw.x);
        const float Ec = bitsel(hm, Em.y, Sw.y);
        // nc = c/(1+Ef) + (Ec-1)/((1+Ei)(Ec+1)), single rcp:
        const float Di = 1.0f + Ei;
        const float Df = 1.0f + Ef;
        const float P = Di * (Ec + 1.0f);
        const float num = fmaf(c[i], P, (Ec - 1.0f) * Df);
        const float nc = num * rcp_(Df * P);
        // h = sigmoid(og)*tanh(nc) = (1-En)/((1+En)(1+Eo)), single rcp:
        const float En = ex2(-2.0f * LOG2E * nc);
        const float hn = (1.0f - En) * rcp_((1.0f + En) * (1.0f + Eo));
        c[i] = nc;
        h[i] = hn;
        b3[i] = bcast4<3>(hn);
      }
    }
  }

  if (half == 0) {
#pragma unroll
    for (int i = 0; i < NNODE; ++i) ho[(i * BS + b) * 4 + d] = h[i];
  }
}

// grid (256, 2) x block 256 -> 2048 waves = 2/SIMD, 512 blocks = 2 blocks/CU
// (LDS 52.8 KB x2 = 105.6 KB <= 160 KB).
__global__ __launch_bounds__(256, 2) void rnn_kernel(
    const float* __restrict__ x,
    const float* __restrict__ h0f, const float* __restrict__ c0f,
    const float* __restrict__ h0b, const float* __restrict__ c0b,
    const float* __restrict__ Wxf, const float* __restrict__ Whf,
    const float* __restrict__ Wnf, const float* __restrict__ bf,
    const float* __restrict__ Wxb, const float* __restrict__ Whb,
    const float* __restrict__ Wnb, const float* __restrict__ bb_) {
  __shared__ float xs[TCH * NNODE * XPAD];  // 52,800 B
  const int tid = threadIdx.x;
  const int b = blockIdx.x * CPB + (tid >> 3);
  const float* xblk = x + (size_t)(blockIdx.x * CPB) * (NNODE * TT);
  if (blockIdx.y == 0) {
    rnn_run<0>(tid, xblk, xs, h0f, c0f, Wxf, Whf, Wnf, bf, g_hf, b);
  } else {
    rnn_run<1>(tid, xblk, xs, h0b, c0b, Wxb, Whb, Wnb, bb_, g_hb, b);
  }
}

// H(b,200) -> sigmoid(H@Wff+bff) -> softmax(ff@Wout+bout).
__global__ __launch_bounds__(128) void ff_kernel(
    const float* __restrict__ Wff, const float* __restrict__ bff,
    const float* __restrict__ Wout, const float* __restrict__ bout,
    float* __restrict__ out) {
  __shared__ float Hs[8][200];
  __shared__ float ffs[8][129];
  const int tid = threadIdx.x;
  const int b0 = blockIdx.x * 8;

  for (int idx = tid; idx < 8 * 200; idx += 128) {
    const int bb = idx / 200;
    const int k = idx - bb * 200;
    const int i = k >> 3;
    const int dd = k & 7;
    const int b = b0 + bb;
    Hs[bb][k] = (dd < 4) ? g_hf[(i * BS + b) * 4 + dd]
                         : g_hb[(i * BS + b) * 4 + (dd - 4)];
  }
  __syncthreads();

  float acc[8];
  const float bv = bff[tid];
#pragma unroll
  for (int bb = 0; bb < 8; ++bb) acc[bb] = bv;
  for (int k = 0; k < 200; ++k) {
    const float w = Wff[k * 128 + tid];
#pragma unroll
    for (int bb = 0; bb < 8; ++bb) acc[bb] = fmaf(Hs[bb][k], w, acc[bb]);
  }
#pragma unroll
  for (int bb = 0; bb < 8; ++bb)
    ffs[bb][tid] = rcp_(1.0f + ex2(-LOG2E * acc[bb]));
  __syncthreads();

  if (tid < 8) {
    float z0 = bout[0], z1 = bout[1];
    for (int n = 0; n < 128; ++n) {
      const float f = ffs[tid][n];
      z0 = fmaf(f, Wout[n * 2 + 0], z0);
      z1 = fmaf(f, Wout[n * 2 + 1], z1);
    }
    const float m = fmaxf(z0, z1);
    const float e0 = ex2(LOG2E * (z0 - m)), e1 = ex2(LOG2E * (z1 - m));
    const float s = rcp_(e0 + e1);
    out[(size_t)(b0 + tid) * 2 + 0] = e0 * s;
    out[(size_t)(b0 + tid) * 2 + 1] = e1 * s;
  }
}

extern "C" void kernel_launch(void* const* d_in, const int* in_sizes, int n_in,
                              void* d_out, int out_size, void* d_ws, size_t ws_size,
                              hipStream_t stream) {
  (void)in_sizes; (void)n_in; (void)out_size; (void)d_ws; (void)ws_size;
  const float* x    = (const float*)d_in[0];
  const float* h0f  = (const float*)d_in[1];
  const float* c0f  = (const float*)d_in[2];
  const float* h0b  = (const float*)d_in[3];
  const float* c0b  = (const float*)d_in[4];
  const float* Wxf  = (const float*)d_in[5];
  const float* Whf  = (const float*)d_in[6];
  const float* Wnf  = (const float*)d_in[7];
  const float* bf   = (const float*)d_in[8];
  const float* Wxb  = (const float*)d_in[9];
  const float* Whb  = (const float*)d_in[10];
  const float* Wnb  = (const float*)d_in[11];
  const float* bb   = (const float*)d_in[12];
  const float* Wff  = (const float*)d_in[13];
  const float* bff  = (const float*)d_in[14];
  const float* Wout = (const float*)d_in[15];
  const float* bout = (const float*)d_in[16];
  float* out = (float*)d_out;

  rnn_kernel<<<dim3(256, 2), dim3(256), 0, stream>>>(
      x, h0f, c0f, h0b, c0b, Wxf, Whf, Wnf, bf, Wxb, Whb, Wnb, bb);
  ff_kernel<<<dim3(1024), dim3(128), 0, stream>>>(Wff, bff, Wout, bout, out);
}

// Round 4
// 577.054 us; speedup vs baseline: 1.3855x; 1.3855x over previous
//
#include <hip/hip_runtime.h>
#include <stddef.h>

#define BS 8192
#define NNODE 25
#define TT 128
#define TCH 16                 // t-steps per staged LDS window
#define NW (TT / TCH)          // 8 windows
#define XPAD 65                // chain-dim stride: 65 = 64+1 -> bank spread
#define LOG2E 1.4426950408889634f

typedef float v2f __attribute__((ext_vector_type(2)));
typedef float v4f __attribute__((ext_vector_type(4)));

// Raw v_exp_f32 / v_rcp_f32. (__exp2f collides with glibc math.h macros.)
__device__ __forceinline__ float ex2(float x) { return __builtin_amdgcn_exp2f(x); }
__device__ __forceinline__ float rcp_(float x) { return __builtin_amdgcn_rcpf(x); }

// Static device buffers (no ws_size dependence). Fully rewritten every call.
__device__ float g_hf[NNODE * BS * 4];  // (i, b, d)
__device__ float g_hb[NNODE * BS * 4];

// Broadcast lane K of each quad (lanes 4q..4q+3) via DPP quad_perm — 1 VALU op.
template <int K>
__device__ __forceinline__ float bcast4(float v) {
  int s = __builtin_bit_cast(int, v);
  int r = __builtin_amdgcn_update_dpp(0, s, (K * 0x55), 0xF, 0xF, true);
  return __builtin_bit_cast(float, r);
}

// Packed gate accumulate: A(ig',fg') B(og',cc') += splat(s) * w.
__device__ __forceinline__ void acc2(v2f& A, v2f& B, float s, v2f wa, v2f wb) {
  v2f sv = {s, s};
  A = __builtin_elementwise_fma(sv, wa, A);
  B = __builtin_elementwise_fma(sv, wb, B);
}

// Full recurrence for one direction; DIR compile-time so staging index math
// and neighbor-row mapping are static. Block = 256 threads = 64 chains.
//
// R4 restructure: per timestep, rows are processed 0..4. For each row, the
// partial gate sums P[j] (all terms EXCEPT lf) are computed first for all 5
// nodes — these depend only on prev-timestep state and on row r-1 (finished).
// The serial sweep then adds the single lf FMA (b3[i-1], the one true
// same-timestep serial dependency) and runs exp/tail. This shortens the
// serial link from 9-FMA-chain+exp+tail to 1-FMA+exp+tail and gives the
// scheduler ~16 independent FMAs per node to fill stall shadows. Instruction
// count/mix identical to the 452 us R1 kernel; only dependency order changed.
template <int DIR>
__device__ __forceinline__ void rnn_run(
    int tid, const float* __restrict__ xblk, float* __restrict__ xs,
    const float* __restrict__ h0, const float* __restrict__ c0,
    const float* __restrict__ Wx, const float* __restrict__ Wh,
    const float* __restrict__ Wn, const float* __restrict__ Bb,
    float* __restrict__ ho, int b) {
  const int d = tid & 3;
  const int bl = tid >> 2;  // local chain 0..63
  const int cI = d, cF = 4 + d, cO = 8 + d, cC = 12 + d;
  const float sS = -LOG2E, sC = 2.0f * LOG2E;

  // Packed prescaled weights. Input order k: 0=x, 1..4=h feats, 5..8=nb
  // [up,dn,lf,rt]. fwd rows [up,dn,lf,rt]=0,1,2,3; bwd order is [up,dn,rt,lf]
  // so lf-value uses row 3, rt-value row 2.
  v2f wA[9], wB[9];
  wA[0] = v2f{sS * Wx[cI], sS * Wx[cF]};
  wB[0] = v2f{sS * Wx[cO], sC * Wx[cC]};
#pragma unroll
  for (int k = 0; k < 4; ++k) {
    wA[1 + k] = v2f{sS * Wh[k * 16 + cI], sS * Wh[k * 16 + cF]};
    wB[1 + k] = v2f{sS * Wh[k * 16 + cO], sC * Wh[k * 16 + cC]};
  }
  const int nrow[4] = {0, 1, DIR ? 3 : 2, DIR ? 2 : 3};
#pragma unroll
  for (int k = 0; k < 4; ++k) {
    wA[5 + k] = v2f{sS * Wn[nrow[k] * 16 + cI], sS * Wn[nrow[k] * 16 + cF]};
    wB[5 + k] = v2f{sS * Wn[nrow[k] * 16 + cO], sC * Wn[nrow[k] * 16 + cC]};
  }
  const v2f bA = {sS * Bb[cI], sS * Bb[cF]};
  const v2f bB = {sS * Bb[cO], sC * Bb[cC]};

  float h[NNODE], c[NNODE], b3[NNODE];
#pragma unroll
  for (int i = 0; i < NNODE; ++i) {
    h[i] = h0[(i * BS + b) * 4 + d];
    c[i] = c0[(i * BS + b) * 4 + d];
    b3[i] = bcast4<3>(h[i]);
  }

  const int t4 = tid & 3;
  const int s0 = tid >> 2;

  for (int w = 0; w < NW; ++w) {
    __syncthreads();  // previous window's reads complete before overwrite
    // Stage window w: logical steps s=16w..16w+15 (bwd: t = 127-s).
    // Each thread: 25 float4 global loads (64B-aligned segments, every byte
    // consumed) -> 100 scalar LDS writes into xs[kk][i][bl] (stride XPAD).
#pragma unroll
    for (int r = 0; r < NNODE; ++r) {
      const int seg = s0 + 64 * r;       // 0..1599
      const int sbl = seg / 25;          // chain
      const int sii = seg - sbl * 25;    // node
      const int tb = (DIR ? (TT - TCH - TCH * w) : (TCH * w)) + 4 * t4;
      const v4f v = *(const v4f*)(xblk + ((size_t)sbl * NNODE + sii) * TT + tb);
#pragma unroll
      for (int j = 0; j < 4; ++j) {
        const int kk = DIR ? (15 - 4 * t4 - j) : (4 * t4 + j);
        xs[(kk * NNODE + sii) * XPAD + sbl] = v[j];
      }
    }
    __syncthreads();

#pragma unroll 1  // keep I$ small: body is the unrolled 25-node step
    for (int kk = 0; kk < TCH; ++kk) {
      // Batch the 25 x reads (quad-broadcast, conflict-free across quads).
      float xq[NNODE];
#pragma unroll
      for (int i = 0; i < NNODE; ++i) xq[i] = xs[(kk * NNODE + i) * XPAD + bl];

#pragma unroll
      for (int r = 0; r < 5; ++r) {
        // Phase A: partial gate sums for the whole row — every term except
        // lf. up (b3[i-5]) is same-t but row r-1 is already finished; dn/rt/
        // self/h-feats are prev-t (P is materialized before this row's sweep
        // overwrites anything it reads). All 5 nodes independent.
        v2f PA[5], PB[5];
#pragma unroll
        for (int j = 0; j < 5; ++j) {
          const int i = r * 5 + j;
          const float f0 = bcast4<0>(h[i]);
          const float f1 = bcast4<1>(h[i]);
          const float f2 = bcast4<2>(h[i]);
          v2f A = bA, B = bB;
          acc2(A, B, xq[i], wA[0], wB[0]);
          acc2(A, B, f0, wA[1], wB[1]);
          acc2(A, B, f1, wA[2], wB[2]);
          acc2(A, B, f2, wA[3], wB[3]);
          acc2(A, B, b3[i], wA[4], wB[4]);
          if (i >= 5) acc2(A, B, b3[i - 5], wA[5], wB[5]);  // up (this t)
          if (i < 20) acc2(A, B, b3[i + 5], wA[6], wB[6]);  // dn (prev t)
          if (i < 24) acc2(A, B, b3[i + 1], wA[8], wB[8]);  // rt (prev t)
          PA[j] = A;
          PB[j] = B;
        }

        // Phase B: serial sweep — single lf FMA is the only same-t link.
#pragma unroll
        for (int j = 0; j < 5; ++j) {
          const int i = r * 5 + j;
          v2f A = PA[j], B = PB[j];
          if (i >= 1) acc2(A, B, b3[i - 1], wA[7], wB[7]);  // lf (serial dep)

          // A = (-log2e*ig, -log2e*fg), B = (-log2e*og, 2log2e*cc)
          const float Ei = ex2(A.x);  // e^-ig
          const float Ef = ex2(A.y);  // e^-fg
          const float Eo = ex2(B.x);  // e^-og
          const float Ec = ex2(B.y);  // e^{2cc}
          // nc = c/(1+Ef) + (Ec-1)/((1+Ei)(Ec+1)), single rcp:
          const float Di = 1.0f + Ei;
          const float Df = 1.0f + Ef;
          const float P = Di * (Ec + 1.0f);
          const float num = fmaf(c[i], P, (Ec - 1.0f) * Df);
          const float nc = num * rcp_(Df * P);
          // h = sigmoid(og)*tanh(nc) = (1-En)/((1+En)(1+Eo)), single rcp:
          const float En = ex2(-2.0f * LOG2E * nc);
          const float hn = (1.0f - En) * rcp_((1.0f + En) * (1.0f + Eo));
          c[i] = nc;
          h[i] = hn;
          b3[i] = bcast4<3>(hn);
        }
      }
    }
  }

#pragma unroll
  for (int i = 0; i < NNODE; ++i) ho[(i * BS + b) * 4 + d] = h[i];
}

// Quad scheme: 4 lanes per (batch, dir) chain; lane d owns feature d and gate
// cols {d,4+d,8+d,12+d}. grid (128, 2) x block 256 -> 1024 waves = 1/SIMD,
// 256 blocks = 1 block/CU (LDS 104 KB caps it there anyway). R3 proved
// >1 wave/SIMD multiplies per-SIMD issue and regresses — keep 1/SIMD.
__global__ __launch_bounds__(256, 1) void rnn_kernel(
    const float* __restrict__ x,
    const float* __restrict__ h0f, const float* __restrict__ c0f,
    const float* __restrict__ h0b, const float* __restrict__ c0b,
    const float* __restrict__ Wxf, const float* __restrict__ Whf,
    const float* __restrict__ Wnf, const float* __restrict__ bf,
    const float* __restrict__ Wxb, const float* __restrict__ Whb,
    const float* __restrict__ Wnb, const float* __restrict__ bb_) {
  __shared__ float xs[TCH * NNODE * XPAD];  // 104,000 B
  const int tid = threadIdx.x;
  const int b = blockIdx.x * 64 + (tid >> 2);
  const float* xblk = x + (size_t)(blockIdx.x * 64) * (NNODE * TT);
  if (blockIdx.y == 0) {
    rnn_run<0>(tid, xblk, xs, h0f, c0f, Wxf, Whf, Wnf, bf, g_hf, b);
  } else {
    rnn_run<1>(tid, xblk, xs, h0b, c0b, Wxb, Whb, Wnb, bb_, g_hb, b);
  }
}

// H(b,200) -> sigmoid(H@Wff+bff) -> softmax(ff@Wout+bout).
__global__ __launch_bounds__(128) void ff_kernel(
    const float* __restrict__ Wff, const float* __restrict__ bff,
    const float* __restrict__ Wout, const float* __restrict__ bout,
    float* __restrict__ out) {
  __shared__ float Hs[8][200];
  __shared__ float ffs[8][129];
  const int tid = threadIdx.x;
  const int b0 = blockIdx.x * 8;

  for (int idx = tid; idx < 8 * 200; idx += 128) {
    const int bb = idx / 200;
    const int k = idx - bb * 200;
    const int i = k >> 3;
    const int dd = k & 7;
    const int b = b0 + bb;
    Hs[bb][k] = (dd < 4) ? g_hf[(i * BS + b) * 4 + dd]
                         : g_hb[(i * BS + b) * 4 + (dd - 4)];
  }
  __syncthreads();

  float acc[8];
  const float bv = bff[tid];
#pragma unroll
  for (int bb = 0; bb < 8; ++bb) acc[bb] = bv;
  for (int k = 0; k < 200; ++k) {
    const float w = Wff[k * 128 + tid];
#pragma unroll
    for (int bb = 0; bb < 8; ++bb) acc[bb] = fmaf(Hs[bb][k], w, acc[bb]);
  }
#pragma unroll
  for (int bb = 0; bb < 8; ++bb)
    ffs[bb][tid] = rcp_(1.0f + ex2(-LOG2E * acc[bb]));
  __syncthreads();

  if (tid < 8) {
    float z0 = bout[0], z1 = bout[1];
    for (int n = 0; n < 128; ++n) {
      const float f = ffs[tid][n];
      z0 = fmaf(f, Wout[n * 2 + 0], z0);
      z1 = fmaf(f, Wout[n * 2 + 1], z1);
    }
    const float m = fmaxf(z0, z1);
    const float e0 = ex2(LOG2E * (z0 - m)), e1 = ex2(LOG2E * (z1 - m));
    const float s = rcp_(e0 + e1);
    out[(size_t)(b0 + tid) * 2 + 0] = e0 * s;
    out[(size_t)(b0 + tid) * 2 + 1] = e1 * s;
  }
}

extern "C" void kernel_launch(void* const* d_in, const int* in_sizes, int n_in,
                              void* d_out, int out_size, void* d_ws, size_t ws_size,
                              hipStream_t stream) {
  (void)in_sizes; (void)n_in; (void)out_size; (void)d_ws; (void)ws_size;
  const float* x    = (const float*)d_in[0];
  const float* h0f  = (const float*)d_in[1];
  const float* c0f  = (const float*)d_in[2];
  const float* h0b  = (const float*)d_in[3];
  const float* c0b  = (const float*)d_in[4];
  const float* Wxf  = (const float*)d_in[5];
  const float* Whf  = (const float*)d_in[6];
  const float* Wnf  = (const float*)d_in[7];
  const float* bf   = (const float*)d_in[8];
  const float* Wxb  = (const float*)d_in[9];
  const float* Whb  = (const float*)d_in[10];
  const float* Wnb  = (const float*)d_in[11];
  const float* bb   = (const float*)d_in[12];
  const float* Wff  = (const float*)d_in[13];
  const float* bff  = (const float*)d_in[14];
  const float* Wout = (const float*)d_in[15];
  const float* bout = (const float*)d_in[16];
  float* out = (float*)d_out;

  rnn_kernel<<<dim3(128, 2), dim3(256), 0, stream>>>(
      x, h0f, c0f, h0b, c0b, Wxf, Whf, Wnf, bf, Wxb, Whb, Wnb, bb);
  ff_kernel<<<dim3(1024), dim3(128), 0, stream>>>(Wff, bff, Wout, bout, out);
}

// Round 5
// 569.509 us; speedup vs baseline: 1.4039x; 1.0132x over previous
//
#include <hip/hip_runtime.h>
#include <stddef.h>

#define BS 8192
#define NNODE 25
#define TT 128
#define TCH 16                 // t-steps per staged LDS window
#define NW (TT / TCH)          // 8 windows
#define XPAD 65                // chain-dim stride: 65 = 64+1 -> bank spread
#define LOG2E 1.4426950408889634f

typedef float v2f __attribute__((ext_vector_type(2)));
typedef float v4f __attribute__((ext_vector_type(4)));

// Raw v_exp_f32 / v_rcp_f32. (__exp2f collides with glibc math.h macros.)
__device__ __forceinline__ float ex2(float x) { return __builtin_amdgcn_exp2f(x); }
__device__ __forceinline__ float rcp_(float x) { return __builtin_amdgcn_rcpf(x); }

// Static device buffers (no ws_size dependence). Fully rewritten every call.
__device__ float g_hf[NNODE * BS * 4];  // (i, b, d)
__device__ float g_hb[NNODE * BS * 4];

// Broadcast lane K of each quad (lanes 4q..4q+3) via DPP quad_perm — 1 VALU op.
template <int K>
__device__ __forceinline__ float bcast4(float v) {
  int s = __builtin_bit_cast(int, v);
  int r = __builtin_amdgcn_update_dpp(0, s, (K * 0x55), 0xF, 0xF, true);
  return __builtin_bit_cast(float, r);
}

// Packed gate accumulate: A(ig',fg') B(og',cc') += splat(s) * w.
__device__ __forceinline__ void acc2(v2f& A, v2f& B, float s, v2f wa, v2f wb) {
  v2f sv = {s, s};
  A = __builtin_elementwise_fma(sv, wa, A);
  B = __builtin_elementwise_fma(sv, wb, B);
}

// Full recurrence for one direction; DIR compile-time so staging index math
// and neighbor-row mapping are static. Block = 256 threads = 64 chains.
//
// Structure locked in by R1/R3/R4 evidence: 4 lanes/chain, 1 wave/SIMD
// (R3: more waves/SIMD scales wall with per-SIMD issue -> regression),
// row-split partial sums (R4, neutral but keeps dep-material exposed).
// Tail uses v_pk_add packing for the 6 independent +1/-1 adds (bit-exact:
// identical IEEE op per element, 3 instrs instead of 6).
template <int DIR>
__device__ __forceinline__ void rnn_run(
    int tid, const float* __restrict__ xblk, float* __restrict__ xs,
    const float* __restrict__ h0, const float* __restrict__ c0,
    const float* __restrict__ Wx, const float* __restrict__ Wh,
    const float* __restrict__ Wn, const float* __restrict__ Bb,
    float* __restrict__ ho, int b) {
  const int d = tid & 3;
  const int bl = tid >> 2;  // local chain 0..63
  const int cI = d, cF = 4 + d, cO = 8 + d, cC = 12 + d;
  const float sS = -LOG2E, sC = 2.0f * LOG2E;

  // Packed prescaled weights. Input order k: 0=x, 1..4=h feats, 5..8=nb
  // [up,dn,lf,rt]. fwd rows [up,dn,lf,rt]=0,1,2,3; bwd order is [up,dn,rt,lf]
  // so lf-value uses row 3, rt-value row 2.
  v2f wA[9], wB[9];
  wA[0] = v2f{sS * Wx[cI], sS * Wx[cF]};
  wB[0] = v2f{sS * Wx[cO], sC * Wx[cC]};
#pragma unroll
  for (int k = 0; k < 4; ++k) {
    wA[1 + k] = v2f{sS * Wh[k * 16 + cI], sS * Wh[k * 16 + cF]};
    wB[1 + k] = v2f{sS * Wh[k * 16 + cO], sC * Wh[k * 16 + cC]};
  }
  const int nrow[4] = {0, 1, DIR ? 3 : 2, DIR ? 2 : 3};
#pragma unroll
  for (int k = 0; k < 4; ++k) {
    wA[5 + k] = v2f{sS * Wn[nrow[k] * 16 + cI], sS * Wn[nrow[k] * 16 + cF]};
    wB[5 + k] = v2f{sS * Wn[nrow[k] * 16 + cO], sC * Wn[nrow[k] * 16 + cC]};
  }
  const v2f bA = {sS * Bb[cI], sS * Bb[cF]};
  const v2f bB = {sS * Bb[cO], sC * Bb[cC]};

  float h[NNODE], c[NNODE], b3[NNODE];
#pragma unroll
  for (int i = 0; i < NNODE; ++i) {
    h[i] = h0[(i * BS + b) * 4 + d];
    c[i] = c0[(i * BS + b) * 4 + d];
    b3[i] = bcast4<3>(h[i]);
  }

  const int t4 = tid & 3;
  const int s0 = tid >> 2;

  for (int w = 0; w < NW; ++w) {
    __syncthreads();  // previous window's reads complete before overwrite
    // Stage window w: logical steps s=16w..16w+15 (bwd: t = 127-s).
    // Each thread: 25 float4 global loads (64B-aligned segments, every byte
    // consumed) -> 100 scalar LDS writes into xs[kk][i][bl] (stride XPAD).
#pragma unroll
    for (int r = 0; r < NNODE; ++r) {
      const int seg = s0 + 64 * r;       // 0..1599
      const int sbl = seg / 25;          // chain
      const int sii = seg - sbl * 25;    // node
      const int tb = (DIR ? (TT - TCH - TCH * w) : (TCH * w)) + 4 * t4;
      const v4f v = *(const v4f*)(xblk + ((size_t)sbl * NNODE + sii) * TT + tb);
#pragma unroll
      for (int j = 0; j < 4; ++j) {
        const int kk = DIR ? (15 - 4 * t4 - j) : (4 * t4 + j);
        xs[(kk * NNODE + sii) * XPAD + sbl] = v[j];
      }
    }
    __syncthreads();

#pragma unroll 1  // keep I$ small: body is the unrolled 25-node step
    for (int kk = 0; kk < TCH; ++kk) {
      // Batch the 25 x reads (quad-broadcast, conflict-free across quads).
      float xq[NNODE];
#pragma unroll
      for (int i = 0; i < NNODE; ++i) xq[i] = xs[(kk * NNODE + i) * XPAD + bl];

#pragma unroll
      for (int r = 0; r < 5; ++r) {
        // Phase A: partial gate sums for the whole row — every term except
        // lf. up (b3[i-5]) is same-t but row r-1 is already finished; dn/rt/
        // self/h-feats are prev-t. All 5 nodes independent.
        v2f PA[5], PB[5];
#pragma unroll
        for (int j = 0; j < 5; ++j) {
          const int i = r * 5 + j;
          const float f0 = bcast4<0>(h[i]);
          const float f1 = bcast4<1>(h[i]);
          const float f2 = bcast4<2>(h[i]);
          v2f A = bA, B = bB;
          acc2(A, B, xq[i], wA[0], wB[0]);
          acc2(A, B, f0, wA[1], wB[1]);
          acc2(A, B, f1, wA[2], wB[2]);
          acc2(A, B, f2, wA[3], wB[3]);
          acc2(A, B, b3[i], wA[4], wB[4]);
          if (i >= 5) acc2(A, B, b3[i - 5], wA[5], wB[5]);  // up (this t)
          if (i < 20) acc2(A, B, b3[i + 5], wA[6], wB[6]);  // dn (prev t)
          if (i < 24) acc2(A, B, b3[i + 1], wA[8], wB[8]);  // rt (prev t)
          PA[j] = A;
          PB[j] = B;
        }

        // Phase B: serial sweep — single lf FMA is the only same-t link.
#pragma unroll
        for (int j = 0; j < 5; ++j) {
          const int i = r * 5 + j;
          v2f A = PA[j], B = PB[j];
          if (i >= 1) acc2(A, B, b3[i - 1], wA[7], wB[7]);  // lf (serial dep)

          // A = (-log2e*ig, -log2e*fg), B = (-log2e*og, 2log2e*cc)
          const float Ei = ex2(A.x);  // e^-ig
          const float Ef = ex2(A.y);  // e^-fg
          const float Eo = ex2(B.x);  // e^-og
          const float Ec = ex2(B.y);  // e^{2cc}
          // Packed +1/-1 adds (bit-exact, 3 pk_add replace 6 scalar adds):
          const v2f Dif = v2f{Ei, Ef} + v2f{1.0f, 1.0f};   // (1+Ei, 1+Ef)
          const v2f Ecpm = v2f{Ec, Ec} + v2f{1.0f, -1.0f}; // (Ec+1, Ec-1)
          // nc = c/(1+Ef) + (Ec-1)/((1+Ei)(Ec+1)), single rcp:
          const float P = Dif.x * Ecpm.x;
          const float num = fmaf(c[i], P, Ecpm.y * Dif.y);
          const float nc = num * rcp_(Dif.y * P);
          // h = sigmoid(og)*tanh(nc) = (1-En)/((1+En)(1+Eo)), single rcp:
          const float En = ex2(-2.0f * LOG2E * nc);
          const v2f Uno = v2f{En, Eo} + v2f{1.0f, 1.0f};   // (1+En, 1+Eo)
          const float hn = (1.0f - En) * rcp_(Uno.x * Uno.y);
          c[i] = nc;
          h[i] = hn;
          b3[i] = bcast4<3>(hn);
        }
      }
    }
  }

#pragma unroll
  for (int i = 0; i < NNODE; ++i) ho[(i * BS + b) * 4 + d] = h[i];
}

// Quad scheme: 4 lanes per (batch, dir) chain; lane d owns feature d and gate
// cols {d,4+d,8+d,12+d}. grid (128, 2) x block 256 -> 1024 waves = 1/SIMD,
// 256 blocks = 1 block/CU (LDS 104 KB caps it there anyway). R3 proved
// >1 wave/SIMD multiplies per-SIMD issue and regresses — keep 1/SIMD.
__global__ __launch_bounds__(256, 1) void rnn_kernel(
    const float* __restrict__ x,
    const float* __restrict__ h0f, const float* __restrict__ c0f,
    const float* __restrict__ h0b, const float* __restrict__ c0b,
    const float* __restrict__ Wxf, const float* __restrict__ Whf,
    const float* __restrict__ Wnf, const float* __restrict__ bf,
    const float* __restrict__ Wxb, const float* __restrict__ Whb,
    const float* __restrict__ Wnb, const float* __restrict__ bb_) {
  __shared__ float xs[TCH * NNODE * XPAD];  // 104,000 B
  const int tid = threadIdx.x;
  const int b = blockIdx.x * 64 + (tid >> 2);
  const float* xblk = x + (size_t)(blockIdx.x * 64) * (NNODE * TT);
  if (blockIdx.y == 0) {
    rnn_run<0>(tid, xblk, xs, h0f, c0f, Wxf, Whf, Wnf, bf, g_hf, b);
  } else {
    rnn_run<1>(tid, xblk, xs, h0b, c0b, Wxb, Whb, Wnb, bb_, g_hb, b);
  }
}

// H(b,200) -> sigmoid(H@Wff+bff) -> softmax(ff@Wout+bout).
// R5 rewrite: 256 blocks x 256 threads, 32 batches/block.
//  - H staging: fully-coalesced float4 loads (consecutive lanes ->
//    consecutive 16B of g_hf/g_hb).
//  - GEMV: thread = (n, batch-half); Hs reads are wave-uniform -> LDS
//    broadcast; Wff loads coalesced 256B/wave, L2-resident.
//  - Output: 64 threads (batch x class), lane-pair shfl softmax. Same float
//    op sequence per element as the old kernel -> bit-exact.
__global__ __launch_bounds__(256) void ff_kernel(
    const float* __restrict__ Wff, const float* __restrict__ bff,
    const float* __restrict__ Wout, const float* __restrict__ bout,
    float* __restrict__ out) {
  __shared__ float Hs[32][200];   // 25,600 B
  __shared__ float ffs[32][130];  // 16,640 B (pad 130 -> bank spread)
  const int tid = threadIdx.x;
  const int b0 = blockIdx.x * 32;

  // Stage H: idx -> (node i, dir, batch bb). Consecutive tid = consecutive
  // bb -> consecutive float4 addresses within one dir array.
  for (int idx = tid; idx < NNODE * 2 * 32; idx += 256) {
    const int i = idx >> 6;          // node 0..24
    const int r = idx & 63;
    const int dir = r >> 5;          // 0: fwd, 1: bwd
    const int bb = r & 31;           // batch within block
    const float* src = dir ? g_hb : g_hf;
    const v4f v = *(const v4f*)(src + ((size_t)(i * BS + b0 + bb)) * 4);
#pragma unroll
    for (int f = 0; f < 4; ++f) Hs[bb][i * 8 + dir * 4 + f] = v[f];
  }
  __syncthreads();

  // ff = sigmoid(H @ Wff + bff): thread (n = tid&127, half = tid>>7) owns
  // 16 batches' accumulator for column n.
  {
    const int n = tid & 127;
    const int half = tid >> 7;  // batches [half*16, half*16+16)
    float acc[16];
    const float bv = bff[n];
#pragma unroll
    for (int q = 0; q < 16; ++q) acc[q] = bv;
    for (int k = 0; k < 200; ++k) {
      const float w = Wff[k * 128 + n];
#pragma unroll
      for (int q = 0; q < 16; ++q)
        acc[q] = fmaf(Hs[half * 16 + q][k], w, acc[q]);
    }
#pragma unroll
    for (int q = 0; q < 16; ++q)
      ffs[half * 16 + q][n] = rcp_(1.0f + ex2(-LOG2E * acc[q]));
  }
  __syncthreads();

  // out = softmax(ff @ Wout + bout): 64 threads = 32 batches x 2 classes,
  // all within wave 0 -> shfl_xor(.,1) pairs (bb, j=0) with (bb, j=1).
  if (tid < 64) {
    const int bb = tid >> 1;
    const int j = tid & 1;
    float z = bout[j];
    for (int n = 0; n < 128; ++n)
      z = fmaf(ffs[bb][n], Wout[n * 2 + j], z);
    const float zp = __shfl_xor(z, 1);
    const float m = fmaxf(z, zp);
    const float e = ex2(LOG2E * (z - m));
    const float ep = ex2(LOG2E * (zp - m));
    const float s = rcp_(e + ep);
    out[(size_t)(b0 + bb) * 2 + j] = e * s;
  }
}

extern "C" void kernel_launch(void* const* d_in, const int* in_sizes, int n_in,
                              void* d_out, int out_size, void* d_ws, size_t ws_size,
                              hipStream_t stream) {
  (void)in_sizes; (void)n_in; (void)out_size; (void)d_ws; (void)ws_size;
  const float* x    = (const float*)d_in[0];
  const float* h0f  = (const float*)d_in[1];
  const float* c0f  = (const float*)d_in[2];
  const float* h0b  = (const float*)d_in[3];
  const float* c0b  = (const float*)d_in[4];
  const float* Wxf  = (const float*)d_in[5];
  const float* Whf  = (const float*)d_in[6];
  const float* Wnf  = (const float*)d_in[7];
  const float* bf   = (const float*)d_in[8];
  const float* Wxb  = (const float*)d_in[9];
  const float* Whb  = (const float*)d_in[10];
  const float* Wnb  = (const float*)d_in[11];
  const float* bb   = (const float*)d_in[12];
  const float* Wff  = (const float*)d_in[13];
  const float* bff  = (const float*)d_in[14];
  const float* Wout = (const float*)d_in[15];
  const float* bout = (const float*)d_in[16];
  float* out = (float*)d_out;

  rnn_kernel<<<dim3(128, 2), dim3(256), 0, stream>>>(
      x, h0f, c0f, h0b, c0b, Wxf, Whf, Wnf, bf, Wxb, Whb, Wnb, bb);
  ff_kernel<<<dim3(256), dim3(256), 0, stream>>>(Wff, bff, Wout, bout, out);
}